// Round 24
// baseline (122.532 us; speedup 1.0000x reference)
//
#include <hip/hip_runtime.h>

#define NN 100000
#define NE 3200000
#define DIN 128
#define DHID 16
#define DOUT 2
#define BSH 7                // 128 dsts per bucket (proven R17)
#define BSZ 128
#define NBUCK ((NN + BSZ - 1) / BSZ)   // 782
#define CAPSH 13             // fixed stripe: 8192 slots/bucket (mean 4092, +64 sigma)
#define CAP (1 << CAPSH)
#define EPT 16               // edges per thread in fill (16 proven best)
#define BHT 1024             // threads in fill blocks
#define EPB (BHT * EPT)      // 16384 edges per block
#define NBB ((NE + EPB - 1) / EPB)  // 196
#define P2CAP 5120           // LDS edge buffer (20 KB); avg bucket 4092
#define P2T 512              // pass2 threads (512 proven R14)
#define P2IT (P2CAP / P2T)   // 10 max fits-path iterations

// round-to-nearest-even f32 -> bf16 (bits)
__device__ __forceinline__ unsigned f2bf(float f) {
    unsigned u = __float_as_uint(f);
    return (u + 0x7FFFu + ((u >> 16) & 1u)) >> 16;
}
__device__ __forceinline__ float bflo(unsigned a) { return __uint_as_float(a << 16); }
__device__ __forceinline__ float bfhi(unsigned a) { return __uint_as_float(a & 0xFFFF0000u); }

// ---------------- bucket cursor zero ----------------
// (R18: runtime fillBuffer for 3 KB costs more than this kernel.
//  R21: cooperative grid.sync ~100 us/sync at 782 blocks — kernel
//  boundaries are the cheap global barrier on gfx950.)
__global__ __launch_bounds__(1024) void k_zero_b(int* __restrict__ bcursor) {
    for (int i = threadIdx.x; i < NBUCK; i += 1024) bcursor[i] = 0;
}

// ------ bucket the edges into fixed stripes: packed[b*CAP + n] ------------
// Atomic-return offsets: pass A's atomicAdd return IS the within-block-
// bucket slot; write pass needs no atomics (R20).
__global__ __launch_bounds__(BHT) void k_bfill(const int* __restrict__ src,
                                               const int* __restrict__ dst,
                                               int* __restrict__ bcursor,
                                               unsigned* __restrict__ packed) {
    __shared__ int h[NBUCK];     // block-local hist
    __shared__ int hbase[NBUCK]; // reserved stripe-local base per bucket
    int t = threadIdx.x;
    for (int i = t; i < NBUCK; i += BHT) h[i] = 0;
    __syncthreads();
    long long base = (long long)blockIdx.x * EPB;
    int ed[EPT], es[EPT], boff[EPT];
#pragma unroll
    for (int k = 0; k < EPT; ++k) {
        long long e = base + (long long)k * BHT + t;
        if (e < NE) {
            ed[k] = dst[e];
            es[k] = src[e];
            boff[k] = atomicAdd(&h[((unsigned)ed[k]) >> BSH], 1);
        } else {
            ed[k] = -1;
            es[k] = 0;
            boff[k] = 0;
        }
    }
    __syncthreads();
    for (int i = t; i < NBUCK; i += BHT) {
        int c = h[i];
        hbase[i] = c ? atomicAdd(&bcursor[i], c) : 0;
    }
    __syncthreads();
#pragma unroll
    for (int k = 0; k < EPT; ++k) {
        if (ed[k] >= 0) {
            unsigned d = (unsigned)ed[k];
            int b = d >> BSH;
            packed[((size_t)b << CAPSH) + hbase[b] + boff[k]] =
                ((d & (BSZ - 1u)) << 24) | (unsigned)es[k];
        }
    }
}

// ------- pass2 + fused mm1 tail: sort bucket stripe, then transform --------
// (a) x prefetched into registers at top (T14); (b) wave-level shfl_up scan;
// (c) fits-path scatter uses phase-1 atomic-return offsets (no atomics);
// (d) R23: W1 staged in LDS as bf16x2 — phase-4 reads ds_read_b64 (~6cyc)
//     instead of b128 (~12cyc); phase 4 was LDS-read-throughput-bound.
__global__ __launch_bounds__(P2T) void k_pass2mm1(const int* __restrict__ bcount,
                                                  const unsigned* __restrict__ packed,
                                                  const float* __restrict__ x,
                                                  const float* __restrict__ W1,
                                                  int* __restrict__ rowstart,
                                                  int* __restrict__ rowcnt,
                                                  float* __restrict__ dinv,
                                                  int* __restrict__ esrc,
                                                  unsigned* __restrict__ g1b) {
    __shared__ unsigned ebuf[P2CAP];       // 20 KB
    __shared__ unsigned Wb[DIN * DHID / 2]; // 4 KB: bf16x2-packed W1
    __shared__ float dvs[BSZ];             // 512 B
    __shared__ int h[BSZ], cur[BSZ];
    __shared__ int wtot[2];
    int b = blockIdx.x;
    int t = threadIdx.x;
    int dst0 = b << BSH;
    // phase 0: stage W1 as bf16x2; prefetch this thread's x quarter
    for (int i = t; i < DIN * DHID / 2; i += P2T) {
        float w0 = W1[2 * i], w1 = W1[2 * i + 1];
        Wb[i] = f2bf(w0) | (f2bf(w1) << 16);
    }
    int q = t & 3;
    int nl = t >> 2;                  // node-local 0..127
    int vmm = dst0 + nl;
    int vr = (vmm < NN) ? vmm : NN - 1;
    float4 xq[8];
    {
        const float4* xr = (const float4*)(x + (size_t)vr * DIN + q * 32);
#pragma unroll
        for (int i = 0; i < 8; ++i) xq[i] = xr[i];
    }
    int ebeg = b << CAPSH;            // stripe base
    int n = bcount[b];                // bucket count (== final bfill cursor)
    bool fits = (n <= P2CAP);
    if (t < BSZ) h[t] = 0;
    __syncthreads();
    // phase 1: hist (+ buffer); fits path records atomic-return offsets
    int myoff[P2IT];
    if (fits) {
#pragma unroll
        for (int it = 0; it < P2IT; ++it) {
            int i = it * P2T + t;
            if (i < n) {
                unsigned pk = packed[ebeg + i];
                ebuf[i] = pk;
                myoff[it] = atomicAdd(&h[pk >> 24], 1);
            }
        }
    } else {
        for (int i = t; i < n; i += P2T)
            atomicAdd(&h[packed[ebeg + i] >> 24], 1);
    }
    __syncthreads();
    // phase 2: wave-level scan (128 counts = 2 waves; shfl_up, 1 barrier)
    int c = (t < BSZ) ? h[t] : 0;
    int val = c;
    if (t < BSZ) {
#pragma unroll
        for (int d = 1; d < 64; d <<= 1) {
            int y = __shfl_up(val, d);
            if ((t & 63) >= d) val += y;
        }
        if ((t & 63) == 63) wtot[t >> 6] = val;
    }
    __syncthreads();
    int incl = val + ((t >= 64 && t < BSZ) ? wtot[0] : 0);
    int gpos = ebeg + incl - c;       // exclusive prefix, stripe-global
    if (t < BSZ) {
        float dv = rsqrtf((float)(c + 1));
        dvs[t] = dv;
        int v = dst0 + t;
        if (v < NN) {
            rowstart[v] = gpos;
            rowcnt[v] = c;
            dinv[v] = dv;
        }
        cur[t] = gpos;
    }
    __syncthreads();
    // phase 3: scatter esrc — fits path: base + saved offset, NO atomics
    if (fits) {
#pragma unroll
        for (int it = 0; it < P2IT; ++it) {
            int i = it * P2T + t;
            if (i < n) {
                unsigned pk = ebuf[i];
                esrc[cur[pk >> 24] + myoff[it]] = (int)(pk & 0xFFFFFFu);
            }
        }
    } else {
        for (int i = t; i < n; i += P2T) {
            unsigned pk = packed[ebeg + i];
            int pos = atomicAdd(&cur[pk >> 24], 1);
            esrc[pos] = (int)(pk & 0xFFFFFFu);
        }
    }
    // phase 4: mm1 for this block's 128 nodes (4 lanes/node, DPP quad-perm);
    // W via ds_read_b64 of bf16x2 pairs, unpacked with bflo/bfhi.
    if (vmm < NN) {
        const float* xs = (const float*)xq;
        float acc0 = 0.f, acc1 = 0.f, acc2 = 0.f, acc3 = 0.f;
        const uint2* Wb2 = (const uint2*)Wb;  // Wb2[k*4 + q] = ch 4q..4q+3 of row k
#define QSTEP(QQ, CTRL)                                                          \
    _Pragma("unroll")                                                            \
    for (int k = 0; k < 32; ++k) {                                               \
        float xv = __int_as_float(                                               \
            __builtin_amdgcn_mov_dpp(__float_as_int(xs[k]), CTRL, 0xF, 0xF, false)); \
        const uint2 wp = Wb2[(QQ * 32 + k) * 4 + q];                             \
        acc0 = fmaf(xv, bflo(wp.x), acc0);                                       \
        acc1 = fmaf(xv, bfhi(wp.x), acc1);                                       \
        acc2 = fmaf(xv, bflo(wp.y), acc2);                                       \
        acc3 = fmaf(xv, bfhi(wp.y), acc3);                                       \
    }
        QSTEP(0, 0x00)
        QSTEP(1, 0x55)
        QSTEP(2, 0xAA)
        QSTEP(3, 0xFF)
#undef QSTEP
        float dv = dvs[nl];
        unsigned u0 = f2bf(acc0 * dv) | (f2bf(acc1 * dv) << 16);
        unsigned u1 = f2bf(acc2 * dv) | (f2bf(acc3 * dv) << 16);
        ((uint2*)(g1b + (size_t)vmm * 8))[q] = make_uint2(u0, u1);
    }
}

// ---------------- layer 1 gather + fused layer-2 transform ----------------
// 8 lanes/node; lane j owns channels 2j,2j+1; end = beg + rowcnt[v].
__global__ __launch_bounds__(256) void k_gather1mm2(const int* __restrict__ rowstart,
                                                    const int* __restrict__ rowcnt,
                                                    const int* __restrict__ esrc,
                                                    const float* __restrict__ dinv,
                                                    const unsigned* __restrict__ G,
                                                    const float* __restrict__ b1,
                                                    const float* __restrict__ W2,
                                                    float* __restrict__ g2) {
    int t = blockIdx.x * 256 + threadIdx.x;
    int v = t >> 3;
    int j = t & 7;
    if (v >= NN) return;
    int beg = rowstart[v];
    int end = beg + rowcnt[v];
    unsigned a = G[(v << 3) + j];  // self loop
    float c0 = bflo(a), c1 = bfhi(a);
    int p = beg;
    int n4 = beg + ((end - beg) & ~3);
    for (; p < n4; p += 4) {
        int u0 = esrc[p], u1 = esrc[p + 1], u2 = esrc[p + 2], u3 = esrc[p + 3];
        unsigned b0 = G[(u0 << 3) + j];
        unsigned b1w = G[(u1 << 3) + j];
        unsigned b2w = G[(u2 << 3) + j];
        unsigned b3w = G[(u3 << 3) + j];
        c0 += bflo(b0) + bflo(b1w) + bflo(b2w) + bflo(b3w);
        c1 += bfhi(b0) + bfhi(b1w) + bfhi(b2w) + bfhi(b3w);
    }
    for (; p < end; ++p) {
        unsigned b = G[(esrc[p] << 3) + j];
        c0 += bflo(b);
        c1 += bfhi(b);
    }
    float dv = dinv[v];
    // fused mm2: relu(out1 + b1) @ W2, partial over this lane's 2 channels
    float o0 = fmaxf(c0 * dv + b1[2 * j], 0.f);
    float o1 = fmaxf(c1 * dv + b1[2 * j + 1], 0.f);
    float p0 = o0 * W2[(2 * j) * 2 + 0] + o1 * W2[(2 * j + 1) * 2 + 0];
    float p1 = o0 * W2[(2 * j) * 2 + 1] + o1 * W2[(2 * j + 1) * 2 + 1];
    p0 += __shfl_xor(p0, 1); p0 += __shfl_xor(p0, 2); p0 += __shfl_xor(p0, 4);
    p1 += __shfl_xor(p1, 1); p1 += __shfl_xor(p1, 2); p1 += __shfl_xor(p1, 4);
    if (j == 0) {
        float2 w = make_float2(p0 * dv, p1 * dv);
        *(float2*)(g2 + (size_t)v * 2) = w;
    }
}

// ---------------- layer 2 gather: 8 lanes/node = 4 edge-slots x 2 ch -------
__global__ __launch_bounds__(256) void k_gather2(const int* __restrict__ rowstart,
                                                 const int* __restrict__ rowcnt,
                                                 const int* __restrict__ esrc,
                                                 const float* __restrict__ dinv,
                                                 const float* __restrict__ g2,
                                                 const float* __restrict__ b2,
                                                 float* __restrict__ out) {
    int t = blockIdx.x * 256 + threadIdx.x;
    int v = t >> 3;
    if (v >= NN) return;
    int lane = t & 7;
    int ch = lane & 1;
    int slot = lane >> 1;
    int beg = rowstart[v];
    int end = beg + rowcnt[v];
    float acc = 0.0f;
    for (int p = beg + slot; p < end; p += 4)
        acc += g2[(esrc[p] << 1) + ch];
    acc += __shfl_xor(acc, 2);
    acc += __shfl_xor(acc, 4);  // all slots summed
    float o = (acc + g2[(v << 1) + ch]) * dinv[v] + b2[ch];
    float other = __shfl_xor(o, 1);
    float m = fmaxf(o, other);
    float lse = m + logf(expf(o - m) + expf(other - m));
    if (slot == 0) out[(v << 1) + ch] = o - lse;
}

extern "C" void kernel_launch(void* const* d_in, const int* in_sizes, int n_in,
                              void* d_out, int out_size, void* d_ws, size_t ws_size,
                              hipStream_t stream) {
    const float* x  = (const float*)d_in[0];
    const float* W1 = (const float*)d_in[1];
    const float* b1 = (const float*)d_in[2];
    const float* W2 = (const float*)d_in[3];
    const float* b2 = (const float*)d_in[4];
    const int* ei   = (const int*)d_in[5];
    const int* src = ei;
    const int* dst = ei + NE;

    // workspace (4B elems). packed/esrc strided: NBUCK*CAP = 6.4M each.
    int* ws       = (int*)d_ws;
    int* bcursor  = ws;                    // 800 (final value = bucket count)
    int* rowstart = ws + 800;              // NN
    int* rowcnt   = ws + 800 + NN;         // NN
    float* dinv   = (float*)(ws + 800 + 2 * NN);      // NN
    unsigned* packed = (unsigned*)(ws + 800 + 3 * NN + 12);  // NBUCK*CAP (16B-aligned)
    int* esrc     = (int*)(packed + (size_t)NBUCK * CAP);    // NBUCK*CAP
    unsigned* g1b = (unsigned*)(esrc + (size_t)NBUCK * CAP); // 8*NN
    float* g2     = (float*)(g1b + 8 * NN); // 2*NN

    float* out = (float*)d_out;

    k_zero_b<<<1, 1024, 0, stream>>>(bcursor);
    k_bfill<<<NBB, BHT, 0, stream>>>(src, dst, bcursor, packed);
    k_pass2mm1<<<NBUCK, P2T, 0, stream>>>(bcursor, packed, x, W1, rowstart, rowcnt, dinv, esrc, g1b);
    k_gather1mm2<<<(NN * 8 + 255) / 256, 256, 0, stream>>>(rowstart, rowcnt, esrc, dinv, g1b, b1, W2, g2);
    k_gather2<<<(NN * 8 + 255) / 256, 256, 0, stream>>>(rowstart, rowcnt, esrc, dinv, g2, b2, out);
}

// Round 25
// 118.707 us; speedup vs baseline: 1.0322x; 1.0322x over previous
//
#include <hip/hip_runtime.h>

#define NN 100000
#define NE 3200000
#define DIN 128
#define DHID 16
#define DOUT 2
#define BSH 7                // 128 dsts per bucket (proven R17)
#define BSZ 128
#define NBUCK ((NN + BSZ - 1) / BSZ)   // 782
#define CAPSH 13             // fixed stripe: 8192 slots/bucket (mean 4092, +64 sigma)
#define CAP (1 << CAPSH)
#define EPT 16               // edges per thread in fill (16 proven best)
#define EPV 4                // int4 vector loads per thread (EPT/4)
#define BHT 1024             // threads in fill blocks
#define EPB (BHT * EPT)      // 16384 edges per block
#define NBB ((NE + EPB - 1) / EPB)  // 196
#define P2CAP 5120           // LDS edge buffer (20 KB); avg bucket 4092
#define P2T 512              // pass2 threads (512 proven R14)
#define P2IT (P2CAP / P2T)   // 10 max fits-path iterations

// round-to-nearest-even f32 -> bf16 (bits)
__device__ __forceinline__ unsigned f2bf(float f) {
    unsigned u = __float_as_uint(f);
    return (u + 0x7FFFu + ((u >> 16) & 1u)) >> 16;
}
__device__ __forceinline__ float bflo(unsigned a) { return __uint_as_float(a << 16); }
__device__ __forceinline__ float bfhi(unsigned a) { return __uint_as_float(a & 0xFFFF0000u); }

// ---------------- bucket cursor zero ----------------
// (R18: runtime fillBuffer for 3 KB costs more than this kernel.
//  R21: cooperative grid.sync ~100 us/sync at 782 blocks.)
__global__ __launch_bounds__(1024) void k_zero_b(int* __restrict__ bcursor) {
    for (int i = threadIdx.x; i < NBUCK; i += 1024) bcursor[i] = 0;
}

// ------ bucket the edges into fixed stripes: packed[b*CAP + n] ------------
// R24: edge loads vectorized as int4 (4 edges / 16B per load; 8 VMEM instrs
// instead of 32). Atomic-return offsets (R20): write pass needs no atomics.
__global__ __launch_bounds__(BHT) void k_bfill(const int* __restrict__ src,
                                               const int* __restrict__ dst,
                                               int* __restrict__ bcursor,
                                               unsigned* __restrict__ packed) {
    __shared__ int h[NBUCK];     // block-local hist
    __shared__ int hbase[NBUCK]; // reserved stripe-local base per bucket
    int t = threadIdx.x;
    for (int i = t; i < NBUCK; i += BHT) h[i] = 0;
    __syncthreads();
    long long base4 = (long long)blockIdx.x * (EPB / 4);  // int4 index base
    const int4* dst4 = (const int4*)dst;
    const int4* src4 = (const int4*)src;
    int ed[EPT], es[EPT], boff[EPT];
#pragma unroll
    for (int k = 0; k < EPV; ++k) {
        long long e4 = base4 + (long long)k * BHT + t;
        if (e4 < NE / 4) {
            int4 d4 = dst4[e4];
            int4 s4 = src4[e4];
            ed[4 * k + 0] = d4.x; ed[4 * k + 1] = d4.y;
            ed[4 * k + 2] = d4.z; ed[4 * k + 3] = d4.w;
            es[4 * k + 0] = s4.x; es[4 * k + 1] = s4.y;
            es[4 * k + 2] = s4.z; es[4 * k + 3] = s4.w;
#pragma unroll
            for (int j = 0; j < 4; ++j)
                boff[4 * k + j] = atomicAdd(&h[((unsigned)ed[4 * k + j]) >> BSH], 1);
        } else {
#pragma unroll
            for (int j = 0; j < 4; ++j) {
                ed[4 * k + j] = -1;
                es[4 * k + j] = 0;
                boff[4 * k + j] = 0;
            }
        }
    }
    __syncthreads();
    for (int i = t; i < NBUCK; i += BHT) {
        int c = h[i];
        hbase[i] = c ? atomicAdd(&bcursor[i], c) : 0;
    }
    __syncthreads();
#pragma unroll
    for (int k = 0; k < EPT; ++k) {
        if (ed[k] >= 0) {
            unsigned d = (unsigned)ed[k];
            int b = d >> BSH;
            packed[((size_t)b << CAPSH) + hbase[b] + boff[k]] =
                ((d & (BSZ - 1u)) << 24) | (unsigned)es[k];
        }
    }
}

// ------- pass2 + fused mm1 tail: sort bucket stripe, then transform --------
// (a) x prefetched into registers at top (T14); (b) wave-level shfl_up scan;
// (c) fits-path scatter uses phase-1 atomic-return offsets (no atomics);
// W staged as f32 / read via ds_read_b128 (R23's bf16-W regressed — phase 4
// is issue/latency-structured, not LDS-throughput-bound).
__global__ __launch_bounds__(P2T) void k_pass2mm1(const int* __restrict__ bcount,
                                                  const unsigned* __restrict__ packed,
                                                  const float* __restrict__ x,
                                                  const float* __restrict__ W1,
                                                  int* __restrict__ rowstart,
                                                  int* __restrict__ rowcnt,
                                                  float* __restrict__ dinv,
                                                  int* __restrict__ esrc,
                                                  unsigned* __restrict__ g1b) {
    __shared__ unsigned ebuf[P2CAP];  // 20 KB
    __shared__ float Ws[DIN * DHID];  // 8 KB
    __shared__ float dvs[BSZ];        // 512 B
    __shared__ int h[BSZ], cur[BSZ];
    __shared__ int wtot[2];
    int b = blockIdx.x;
    int t = threadIdx.x;
    int dst0 = b << BSH;
    // phase 0: stage W1; prefetch this thread's x quarter (consumed phase 4)
    for (int i = t; i < DIN * DHID; i += P2T) Ws[i] = W1[i];
    int q = t & 3;
    int nl = t >> 2;                  // node-local 0..127
    int vmm = dst0 + nl;
    int vr = (vmm < NN) ? vmm : NN - 1;
    float4 xq[8];
    {
        const float4* xr = (const float4*)(x + (size_t)vr * DIN + q * 32);
#pragma unroll
        for (int i = 0; i < 8; ++i) xq[i] = xr[i];
    }
    int ebeg = b << CAPSH;            // stripe base
    int n = bcount[b];                // bucket count (== final bfill cursor)
    bool fits = (n <= P2CAP);
    if (t < BSZ) h[t] = 0;
    __syncthreads();
    // phase 1: hist (+ buffer); fits path records atomic-return offsets
    int myoff[P2IT];
    if (fits) {
#pragma unroll
        for (int it = 0; it < P2IT; ++it) {
            int i = it * P2T + t;
            if (i < n) {
                unsigned pk = packed[ebeg + i];
                ebuf[i] = pk;
                myoff[it] = atomicAdd(&h[pk >> 24], 1);
            }
        }
    } else {
        for (int i = t; i < n; i += P2T)
            atomicAdd(&h[packed[ebeg + i] >> 24], 1);
    }
    __syncthreads();
    // phase 2: wave-level scan (128 counts = 2 waves; shfl_up, 1 barrier)
    int c = (t < BSZ) ? h[t] : 0;
    int val = c;
    if (t < BSZ) {
#pragma unroll
        for (int d = 1; d < 64; d <<= 1) {
            int y = __shfl_up(val, d);
            if ((t & 63) >= d) val += y;
        }
        if ((t & 63) == 63) wtot[t >> 6] = val;
    }
    __syncthreads();
    int incl = val + ((t >= 64 && t < BSZ) ? wtot[0] : 0);
    int gpos = ebeg + incl - c;       // exclusive prefix, stripe-global
    if (t < BSZ) {
        float dv = rsqrtf((float)(c + 1));
        dvs[t] = dv;
        int v = dst0 + t;
        if (v < NN) {
            rowstart[v] = gpos;
            rowcnt[v] = c;
            dinv[v] = dv;
        }
        cur[t] = gpos;
    }
    __syncthreads();
    // phase 3: scatter esrc — fits path: base + saved offset, NO atomics
    if (fits) {
#pragma unroll
        for (int it = 0; it < P2IT; ++it) {
            int i = it * P2T + t;
            if (i < n) {
                unsigned pk = ebuf[i];
                esrc[cur[pk >> 24] + myoff[it]] = (int)(pk & 0xFFFFFFu);
            }
        }
    } else {
        for (int i = t; i < n; i += P2T) {
            unsigned pk = packed[ebeg + i];
            int pos = atomicAdd(&cur[pk >> 24], 1);
            esrc[pos] = (int)(pk & 0xFFFFFFu);
        }
    }
    // phase 4: mm1 for this block's 128 nodes (4 lanes/node, proven DPP);
    // consumes the prefetched xq. Reads Ws/dvs (synced above).
    if (vmm < NN) {
        const float* xs = (const float*)xq;
        float acc0 = 0.f, acc1 = 0.f, acc2 = 0.f, acc3 = 0.f;
#define QSTEP(QQ, CTRL)                                                          \
    _Pragma("unroll")                                                            \
    for (int k = 0; k < 32; ++k) {                                               \
        float xv = __int_as_float(                                               \
            __builtin_amdgcn_mov_dpp(__float_as_int(xs[k]), CTRL, 0xF, 0xF, false)); \
        const float4 w = *(const float4*)&Ws[(QQ * 32 + k) * DHID + q * 4];      \
        acc0 += xv * w.x; acc1 += xv * w.y; acc2 += xv * w.z; acc3 += xv * w.w;  \
    }
        QSTEP(0, 0x00)
        QSTEP(1, 0x55)
        QSTEP(2, 0xAA)
        QSTEP(3, 0xFF)
#undef QSTEP
        float dv = dvs[nl];
        unsigned u0 = f2bf(acc0 * dv) | (f2bf(acc1 * dv) << 16);
        unsigned u1 = f2bf(acc2 * dv) | (f2bf(acc3 * dv) << 16);
        ((uint2*)(g1b + (size_t)vmm * 8))[q] = make_uint2(u0, u1);
    }
}

// ---------------- layer 1 gather + fused layer-2 transform ----------------
// 8 lanes/node; lane j owns channels 2j,2j+1; end = beg + rowcnt[v].
__global__ __launch_bounds__(256) void k_gather1mm2(const int* __restrict__ rowstart,
                                                    const int* __restrict__ rowcnt,
                                                    const int* __restrict__ esrc,
                                                    const float* __restrict__ dinv,
                                                    const unsigned* __restrict__ G,
                                                    const float* __restrict__ b1,
                                                    const float* __restrict__ W2,
                                                    float* __restrict__ g2) {
    int t = blockIdx.x * 256 + threadIdx.x;
    int v = t >> 3;
    int j = t & 7;
    if (v >= NN) return;
    int beg = rowstart[v];
    int end = beg + rowcnt[v];
    unsigned a = G[(v << 3) + j];  // self loop
    float c0 = bflo(a), c1 = bfhi(a);
    int p = beg;
    int n4 = beg + ((end - beg) & ~3);
    for (; p < n4; p += 4) {
        int u0 = esrc[p], u1 = esrc[p + 1], u2 = esrc[p + 2], u3 = esrc[p + 3];
        unsigned b0 = G[(u0 << 3) + j];
        unsigned b1w = G[(u1 << 3) + j];
        unsigned b2w = G[(u2 << 3) + j];
        unsigned b3w = G[(u3 << 3) + j];
        c0 += bflo(b0) + bflo(b1w) + bflo(b2w) + bflo(b3w);
        c1 += bfhi(b0) + bfhi(b1w) + bfhi(b2w) + bfhi(b3w);
    }
    for (; p < end; ++p) {
        unsigned b = G[(esrc[p] << 3) + j];
        c0 += bflo(b);
        c1 += bfhi(b);
    }
    float dv = dinv[v];
    // fused mm2: relu(out1 + b1) @ W2, partial over this lane's 2 channels
    float o0 = fmaxf(c0 * dv + b1[2 * j], 0.f);
    float o1 = fmaxf(c1 * dv + b1[2 * j + 1], 0.f);
    float p0 = o0 * W2[(2 * j) * 2 + 0] + o1 * W2[(2 * j + 1) * 2 + 0];
    float p1 = o0 * W2[(2 * j) * 2 + 1] + o1 * W2[(2 * j + 1) * 2 + 1];
    p0 += __shfl_xor(p0, 1); p0 += __shfl_xor(p0, 2); p0 += __shfl_xor(p0, 4);
    p1 += __shfl_xor(p1, 1); p1 += __shfl_xor(p1, 2); p1 += __shfl_xor(p1, 4);
    if (j == 0) {
        float2 w = make_float2(p0 * dv, p1 * dv);
        *(float2*)(g2 + (size_t)v * 2) = w;
    }
}

// ---------------- layer 2 gather: 8 lanes/node = 4 edge-slots x 2 ch -------
__global__ __launch_bounds__(256) void k_gather2(const int* __restrict__ rowstart,
                                                 const int* __restrict__ rowcnt,
                                                 const int* __restrict__ esrc,
                                                 const float* __restrict__ dinv,
                                                 const float* __restrict__ g2,
                                                 const float* __restrict__ b2,
                                                 float* __restrict__ out) {
    int t = blockIdx.x * 256 + threadIdx.x;
    int v = t >> 3;
    if (v >= NN) return;
    int lane = t & 7;
    int ch = lane & 1;
    int slot = lane >> 1;
    int beg = rowstart[v];
    int end = beg + rowcnt[v];
    float acc = 0.0f;
    for (int p = beg + slot; p < end; p += 4)
        acc += g2[(esrc[p] << 1) + ch];
    acc += __shfl_xor(acc, 2);
    acc += __shfl_xor(acc, 4);  // all slots summed
    float o = (acc + g2[(v << 1) + ch]) * dinv[v] + b2[ch];
    float other = __shfl_xor(o, 1);
    float m = fmaxf(o, other);
    float lse = m + logf(expf(o - m) + expf(other - m));
    if (slot == 0) out[(v << 1) + ch] = o - lse;
}

extern "C" void kernel_launch(void* const* d_in, const int* in_sizes, int n_in,
                              void* d_out, int out_size, void* d_ws, size_t ws_size,
                              hipStream_t stream) {
    const float* x  = (const float*)d_in[0];
    const float* W1 = (const float*)d_in[1];
    const float* b1 = (const float*)d_in[2];
    const float* W2 = (const float*)d_in[3];
    const float* b2 = (const float*)d_in[4];
    const int* ei   = (const int*)d_in[5];
    const int* src = ei;
    const int* dst = ei + NE;

    // workspace (4B elems). packed/esrc strided: NBUCK*CAP = 6.4M each.
    int* ws       = (int*)d_ws;
    int* bcursor  = ws;                    // 800 (final value = bucket count)
    int* rowstart = ws + 800;              // NN
    int* rowcnt   = ws + 800 + NN;         // NN
    float* dinv   = (float*)(ws + 800 + 2 * NN);      // NN
    unsigned* packed = (unsigned*)(ws + 800 + 3 * NN + 12);  // NBUCK*CAP (16B-aligned)
    int* esrc     = (int*)(packed + (size_t)NBUCK * CAP);    // NBUCK*CAP
    unsigned* g1b = (unsigned*)(esrc + (size_t)NBUCK * CAP); // 8*NN
    float* g2     = (float*)(g1b + 8 * NN); // 2*NN

    float* out = (float*)d_out;

    k_zero_b<<<1, 1024, 0, stream>>>(bcursor);
    k_bfill<<<NBB, BHT, 0, stream>>>(src, dst, bcursor, packed);
    k_pass2mm1<<<NBUCK, P2T, 0, stream>>>(bcursor, packed, x, W1, rowstart, rowcnt, dinv, esrc, g1b);
    k_gather1mm2<<<(NN * 8 + 255) / 256, 256, 0, stream>>>(rowstart, rowcnt, esrc, dinv, g1b, b1, W2, g2);
    k_gather2<<<(NN * 8 + 255) / 256, 256, 0, stream>>>(rowstart, rowcnt, esrc, dinv, g2, b2, out);
}